// Round 4
// baseline (1045.011 us; speedup 1.0000x reference)
//
#include <hip/hip_runtime.h>

typedef _Float16 f16;
typedef _Float16 f16x4 __attribute__((ext_vector_type(4)));
typedef _Float16 f16x8 __attribute__((ext_vector_type(8)));
typedef float    f32x4 __attribute__((ext_vector_type(4)));
typedef float    f32x16 __attribute__((ext_vector_type(16)));
typedef unsigned int u32;

#define MFMA32(a,b,c) __builtin_amdgcn_mfma_f32_32x32x16_f16((a),(b),(c),0,0,0)

__device__ __forceinline__ u32 pkf16(float a, float b) {
  return __builtin_bit_cast(u32, __builtin_amdgcn_cvt_pkrtz(a, b));
}
union F8U4 { u32 d[4]; f16x8 v; };

// ---------------- FFT-layout matrices (exact 0/+-1 entries) ----------------
__device__ __forceinline__ float T_val(int rr, int cc) {
  int p = rr >> 2, f = rr & 3;
  int c = cc >> 2, d = (cc >> 1) & 1, e = cc & 1;
  int q = f & 1;
  int m = (p * c + 2 * q * d) & 3;
  float cs = (m == 0) ? 1.f : (m == 2) ? -1.f : 0.f;
  float sn = (m == 1) ? 1.f : (m == 3) ? -1.f : 0.f;
  if (f < 2) return (e == 0) ? cs : sn;
  return (e == 0) ? -sn : cs;
}
__device__ __forceinline__ float U_val(int rr, int cc) {
  int p = rr >> 2, f = rr & 3;
  int c = cc >> 2, d = (cc >> 1) & 1, e = cc & 1;
  int q = f & 1;
  int m = (p * c + 2 * q * d) & 3;
  float cs = (m == 0) ? 1.f : (m == 2) ? -1.f : 0.f;
  float sn = (m == 1) ? 1.f : (m == 3) ? -1.f : 0.f;
  float v;
  if (f < 2) v = (e == 0) ? cs : -sn;
  else       v = (e == 0) ? sn : cs;
  return v * 0.125f;
}

// ---------------- P1: Wq_eff / Wk_eff (fp32) ----------------
__global__ void prep_qk(const float* __restrict__ Wq, const float* __restrict__ Wk,
                        float* __restrict__ WqE, float* __restrict__ WkE) {
  int b = blockIdx.x;
  int isK = b >> 11;
  int h = (b >> 8) & 7;
  int dd = b & 255;
  const float* W = isK ? Wk : Wq;
  float* E = isK ? WkE : WqE;
  int k = threadIdx.x;
  size_t base = (size_t)h * 65536;
  float v;
  if (h < 3) {
    v = W[base + (size_t)dd * 256 + k];
  } else {
    int g = dd >> 4, i = dd & 15;
    float s = 0.f;
    for (int ip = 0; ip < 16; ++ip) {
      float t = T_val(ip, i);
      if (t != 0.f) s += t * W[base + (size_t)(g * 16 + ip) * 256 + k];
    }
    v = s;
  }
  E[base + (size_t)dd * 256 + k] = v;
}

// ---------------- P2: Mt[h][d'][d] = (Wq_eff . Wk_eff^T)[d][d'] / 16 (fp16)
__global__ void prep_m(const float* __restrict__ WqE, const float* __restrict__ WkE,
                       f16* __restrict__ Mt) {
  __shared__ float Aq[32][33];
  __shared__ float Bk[32][33];
  int h = blockIdx.x >> 6;
  int dpt = (blockIdx.x >> 3) & 7;
  int dt = blockIdx.x & 7;
  int tid = threadIdx.x;
  int drow = tid & 31;
  int dprow4 = (tid >> 5) * 4;
  float acc0 = 0.f, acc1 = 0.f, acc2 = 0.f, acc3 = 0.f;
  int r = tid >> 3;
  int c0 = (tid & 7) * 4;
  for (int kt = 0; kt < 8; ++kt) {
    for (int jj = 0; jj < 4; ++jj) {
      Aq[r][c0 + jj] = WqE[(size_t)h * 65536 + (size_t)(dt * 32 + r) * 256 + kt * 32 + c0 + jj];
      Bk[r][c0 + jj] = WkE[(size_t)h * 65536 + (size_t)(dpt * 32 + r) * 256 + kt * 32 + c0 + jj];
    }
    __syncthreads();
    #pragma unroll
    for (int k = 0; k < 32; ++k) {
      float a = Aq[drow][k];
      acc0 += a * Bk[dprow4 + 0][k];
      acc1 += a * Bk[dprow4 + 1][k];
      acc2 += a * Bk[dprow4 + 2][k];
      acc3 += a * Bk[dprow4 + 3][k];
    }
    __syncthreads();
  }
  int d_ = dt * 32 + drow;
  size_t ob = (size_t)h * 65536 + (size_t)(dpt * 32 + dprow4) * 256 + d_;
  Mt[ob + 0 * 256] = (f16)(acc0 * 0.0625f);
  Mt[ob + 1 * 256] = (f16)(acc1 * 0.0625f);
  Mt[ob + 2 * 256] = (f16)(acc2 * 0.0625f);
  Mt[ob + 3 * 256] = (f16)(acc3 * 0.0625f);
}

// ---------------- P3: Wvt[h][k'][d] = Wv_eff[d][k'] / NUM_HEADS (fp16)
__global__ void prep_v(const float* __restrict__ Wv, f16* __restrict__ Wvt) {
  __shared__ float Ts[16][16];
  __shared__ float Us[16][16];
  int h = blockIdx.x >> 8;
  int kp = blockIdx.x & 255;
  int tid = threadIdx.x;
  Ts[tid >> 4][tid & 15] = T_val(tid >> 4, tid & 15);
  Us[tid >> 4][tid & 15] = U_val(tid >> 4, tid & 15);
  __syncthreads();
  int d = tid;
  int g = d >> 4, i = d & 15;
  int gp = kp >> 4, fp = kp & 15;
  float s = 0.f;
  if (h < 3) {
    s = Wv[(size_t)h * 65536 + (size_t)d * 256 + kp];
  } else {
    for (int ip = 0; ip < 16; ++ip) {
      float tv = Ts[ip][i];
      if (tv != 0.f) {
        float inner = 0.f;
        for (int jj = 0; jj < 16; ++jj) {
          float uv = Us[fp][jj];
          if (uv != 0.f)
            inner += uv * Wv[(size_t)h * 65536 + (size_t)(g * 16 + ip) * 256 + gp * 16 + jj];
        }
        s += tv * inner;
      }
    }
  }
  Wvt[(size_t)h * 65536 + (size_t)kp * 256 + d] = (f16)(s * 0.125f);
}

// ---------------- P4: repack to fragment-major for coalesced per-lane loads
// MtF[h][dt][kt][lane][8] = Mt[h][32dt + (l&31)][16kt + 8(l>>5) + j]
// WvF[h][kt'][kt][lane][8] = Wvt[h][32kt' + (l&31)][16kt + 8(l>>5) + j]
__global__ void repack(const f16* __restrict__ Mt, const f16* __restrict__ Wvt,
                       f16* __restrict__ MtF, f16* __restrict__ WvF) {
  int bid = blockIdx.x;            // 2048 = 2*8*128
  int which = bid >> 10;
  int h = (bid >> 7) & 7;
  int dk = bid & 127;
  int dt = dk >> 4, kt = dk & 15;
  int l = threadIdx.x;             // 64
  int r = l & 31, H = l >> 5;
  const f16* src = which ? Wvt : Mt;
  f16* dst = which ? WvF : MtF;
  size_t sb = (size_t)h * 65536 + (size_t)(32 * dt + r) * 256 + 16 * kt + 8 * H;
  size_t db = ((size_t)((h * 8 + dt) * 16 + kt) * 64 + l) * 8;
  #pragma unroll
  for (int j = 0; j < 8; ++j) dst[db + j] = src[sb + j];
}

// ---------------- Main fused kernel ----------------
// 512 thr (8 waves), 4 batches/block, grid 1024. LDS 81920 B:
//   Xs [128 rows][256] f16, full 32-slot XOR swizzle (byte ^ (row&31)<<4)  65536 B
//   Sp [16 r][2 bp][2 b][64 lane] f32 (dq-partial score reduction)         16384 B
// Wave (bp = w>>2, xi = w&3):
//   score: Z'[2b][2dt in xi-quarter] <- MtF(L2) x Xs; S-chain in regs (shfl half-swap);
//          atomicAdd partials -> Sp; softmax redundantly per wave -> P in regs.
//   V:     VC[2b][2 k'-tiles in xi-quarter] <- Xs x WvF(L2); PV in regs -> O (persistent).
__global__ __launch_bounds__(512, 2) void mha_main(
    const float* __restrict__ xg_all,
    const f16* __restrict__ MtF,
    const f16* __restrict__ WvF,
    float* __restrict__ outG)
{
  extern __shared__ char smem[];
  f16*   Xs = (f16*)smem;
  float* Sp = (float*)(smem + 65536);

  const int tid = threadIdx.x;
  const int w   = tid >> 6;
  const int l   = tid & 63;
  const int lr  = l & 31;
  const int H   = l >> 5;
  const int bp  = w >> 2;
  const int xi  = w & 3;

  // ---- stage X (fp32 -> fp16, full-XOR swizzle) + zero Sp ----
  const float* xg = xg_all + (size_t)blockIdx.x * 32768;
  #pragma unroll 4
  for (int i = 0; i < 16; ++i) {
    int f4 = i * 512 + tid;
    int row = f4 >> 6;
    int c8 = (f4 & 63) * 8;               // byte col of this 8B write
    f32x4 v = *(const f32x4*)(xg + (size_t)f4 * 4);
    f16x4 hv;
    hv[0] = (f16)v[0]; hv[1] = (f16)v[1]; hv[2] = (f16)v[2]; hv[3] = (f16)v[3];
    *(f16x4*)((char*)Xs + row * 512 + (c8 ^ ((row & 31) << 4))) = hv;
  }
  #pragma unroll
  for (int i = 0; i < 8; ++i) Sp[i * 512 + tid] = 0.f;
  __syncthreads();

  const int rb0 = ((bp * 2 + 0) * 32 + lr) * 512;   // byte base of batch-0 row
  const int rb1 = ((bp * 2 + 1) * 32 + lr) * 512;
  const int sw  = lr << 4;                          // swizzle mask

  f32x16 O[2][2];
  #pragma unroll
  for (int b = 0; b < 2; ++b)
    #pragma unroll
    for (int n = 0; n < 2; ++n)
      #pragma unroll
      for (int i = 0; i < 16; ++i) O[b][n][i] = 0.f;

  for (int h = 0; h < 8; ++h) {
    // ================= score =================
    {
      f32x16 Z[2][2];
      #pragma unroll
      for (int b = 0; b < 2; ++b)
        #pragma unroll
        for (int d = 0; d < 2; ++d)
          #pragma unroll
          for (int i = 0; i < 16; ++i) Z[b][d][i] = 0.f;

      const f16* A0 = MtF + ((size_t)((h * 8 + 2 * xi + 0) * 16) * 64 + l) * 8;
      const f16* A1 = MtF + ((size_t)((h * 8 + 2 * xi + 1) * 16) * 64 + l) * 8;
      #pragma unroll 4
      for (int kt = 0; kt < 16; ++kt) {
        f16x8 a0 = *(const f16x8*)(A0 + kt * 512);
        f16x8 a1 = *(const f16x8*)(A1 + kt * 512);
        int cb = (kt * 32 + 16 * H) ^ sw;
        f16x8 b0 = *(const f16x8*)((const char*)Xs + rb0 + cb);
        f16x8 b1 = *(const f16x8*)((const char*)Xs + rb1 + cb);
        Z[0][0] = MFMA32(a0, b0, Z[0][0]);
        Z[0][1] = MFMA32(a1, b0, Z[0][1]);
        Z[1][0] = MFMA32(a0, b1, Z[1][0]);
        Z[1][1] = MFMA32(a1, b1, Z[1][1]);
      }

      // S-chain: S^T[t][s] += X[t][d'] * Z'[d'][s], fully in registers
      f32x16 S[2];
      #pragma unroll
      for (int b = 0; b < 2; ++b)
        #pragma unroll
        for (int i = 0; i < 16; ++i) S[b][i] = 0.f;

      #pragma unroll
      for (int b = 0; b < 2; ++b) {
        #pragma unroll
        for (int d = 0; d < 2; ++d) {
          int dt = 2 * xi + d;
          #pragma unroll
          for (int kb = 0; kb < 2; ++kb) {
            u32 u0 = pkf16(Z[b][d][8 * kb + 0], Z[b][d][8 * kb + 1]);
            u32 u1 = pkf16(Z[b][d][8 * kb + 2], Z[b][d][8 * kb + 3]);
            u32 u2 = pkf16(Z[b][d][8 * kb + 4], Z[b][d][8 * kb + 5]);
            u32 u3 = pkf16(Z[b][d][8 * kb + 6], Z[b][d][8 * kb + 7]);
            u32 r0 = (u32)__shfl_xor((int)(H ? u0 : u2), 32);
            u32 r1 = (u32)__shfl_xor((int)(H ? u1 : u3), 32);
            F8U4 Bf;
            Bf.d[0] = H ? r0 : u0;
            Bf.d[1] = H ? r1 : u1;
            Bf.d[2] = H ? u2 : r0;
            Bf.d[3] = H ? u3 : r1;
            f16x8 Af = *(const f16x8*)((const char*)Xs + (b ? rb1 : rb0) +
                                       ((64 * dt + 32 * kb + 16 * H) ^ sw));
            S[b] = MFMA32(Af, Bf.v, S[b]);
          }
        }
      }
      // reduce dq-partials
      #pragma unroll
      for (int b = 0; b < 2; ++b)
        #pragma unroll
        for (int r = 0; r < 16; ++r)
          atomicAdd(&Sp[((r * 2 + bp) * 2 + b) * 64 + l], S[b][r]);
    }
    __syncthreads();   // BAR1: all partials in

    // ---- readback + parity softmax -> P in regs ----
    f16x8 P[2][2];
    {
      #pragma unroll
      for (int b = 0; b < 2; ++b) {
        float e[16];
        float mx = -1e30f;
        #pragma unroll
        for (int r = 0; r < 16; ++r) {
          float v = Sp[((r * 2 + bp) * 2 + b) * 64 + l];
          bool val = ((r & 1) == (lr & 1));
          e[r] = val ? v : -1e30f;
          mx = fmaxf(mx, e[r]);
        }
        mx = fmaxf(mx, __shfl_xor(mx, 32));
        float sm = 0.f;
        #pragma unroll
        for (int r = 0; r < 16; ++r) {
          bool val = ((r & 1) == (lr & 1));
          e[r] = val ? __expf(e[r] - mx) : 0.f;
          sm += e[r];
        }
        sm += __shfl_xor(sm, 32);
        float inv = 1.f / sm;
        #pragma unroll
        for (int kb = 0; kb < 2; ++kb) {
          F8U4 u;
          #pragma unroll
          for (int q = 0; q < 4; ++q)
            u.d[q] = pkf16(e[8 * kb + 2 * q] * inv, e[8 * kb + 2 * q + 1] * inv);
          P[b][kb] = u.v;
        }
      }
    }
    __syncthreads();   // BAR2: all readbacks done
    // zero own share of Sp for next head
    #pragma unroll
    for (int q = 0; q < 4; ++q)
      #pragma unroll
      for (int b = 0; b < 2; ++b)
        Sp[(((4 * xi + q) * 2 + bp) * 2 + b) * 64 + l] = 0.f;
    __syncthreads();   // BAR3: Sp clean

    // ================= V + PV =================
    {
      f32x16 VC[2][2];
      #pragma unroll
      for (int b = 0; b < 2; ++b)
        #pragma unroll
        for (int n = 0; n < 2; ++n)
          #pragma unroll
          for (int i = 0; i < 16; ++i) VC[b][n][i] = 0.f;

      const f16* W0 = WvF + ((size_t)((h * 8 + 2 * xi + 0) * 16) * 64 + l) * 8;
      const f16* W1 = WvF + ((size_t)((h * 8 + 2 * xi + 1) * 16) * 64 + l) * 8;
      #pragma unroll 4
      for (int kt = 0; kt < 16; ++kt) {
        int cb = (kt * 32 + 16 * H) ^ sw;
        f16x8 a0 = *(const f16x8*)((const char*)Xs + rb0 + cb);
        f16x8 a1 = *(const f16x8*)((const char*)Xs + rb1 + cb);
        f16x8 w0 = *(const f16x8*)(W0 + kt * 512);
        f16x8 w1 = *(const f16x8*)(W1 + kt * 512);
        VC[0][0] = MFMA32(a0, w0, VC[0][0]);
        VC[0][1] = MFMA32(a0, w1, VC[0][1]);
        VC[1][0] = MFMA32(a1, w0, VC[1][0]);
        VC[1][1] = MFMA32(a1, w1, VC[1][1]);
      }
      // PV entirely in registers (pi-permutation consistent on both operands)
      #pragma unroll
      for (int b = 0; b < 2; ++b)
        #pragma unroll
        for (int n = 0; n < 2; ++n)
          #pragma unroll
          for (int kb = 0; kb < 2; ++kb) {
            F8U4 u;
            #pragma unroll
            for (int q = 0; q < 4; ++q)
              u.d[q] = pkf16(VC[b][n][8 * kb + 2 * q], VC[b][n][8 * kb + 2 * q + 1]);
            O[b][n] = MFMA32(P[b][kb], u.v, O[b][n]);
          }
    }
  }

  // ---- store O (lane = k', coalesced 128B per instr) ----
  #pragma unroll
  for (int b = 0; b < 2; ++b) {
    float* ob = outG + ((size_t)blockIdx.x * 4 + bp * 2 + b) * 8192;
    #pragma unroll
    for (int n = 0; n < 2; ++n) {
      int kp = 32 * (2 * xi + n) + lr;
      #pragma unroll
      for (int r = 0; r < 16; ++r) {
        int s = (r & 3) + 8 * (r >> 2) + 4 * H;
        ob[s * 256 + kp] = O[b][n][r];
      }
    }
  }
}

// ---------------- launch ----------------
extern "C" void kernel_launch(void* const* d_in, const int* in_sizes, int n_in,
                              void* d_out, int out_size, void* d_ws, size_t ws_size,
                              hipStream_t stream) {
  const float* x  = (const float*)d_in[0];
  const float* Wq = (const float*)d_in[1];
  const float* Wk = (const float*)d_in[2];
  const float* Wv = (const float*)d_in[3];
  float* out = (float*)d_out;
  char* ws = (char*)d_ws;
  float* WqE = (float*)ws;                       // 2 MB (dead after prep_m)
  float* WkE = (float*)(ws + 2097152);           // 2 MB (dead after prep_m)
  f16*   Mt  = (f16*)(ws + 4194304);             // 1 MB fp16
  f16*   Wvt = (f16*)(ws + 5242880);             // 1 MB fp16
  f16*   MtF = (f16*)ws;                         // 1 MB, overlays WqE
  f16*   WvF = (f16*)(ws + 2097152);             // 1 MB, overlays WkE

  prep_qk<<<4096, 256, 0, stream>>>(Wq, Wk, WqE, WkE);
  prep_m<<<512, 256, 0, stream>>>(WqE, WkE, Mt);
  prep_v<<<2048, 256, 0, stream>>>(Wv, Wvt);
  repack<<<2048, 64, 0, stream>>>(Mt, Wvt, MtF, WvF);
  mha_main<<<1024, 512, 81920, stream>>>(x, MtF, WvF, out);
}

// Round 5
// 430.585 us; speedup vs baseline: 2.4270x; 2.4270x over previous
//
#include <hip/hip_runtime.h>

typedef _Float16 f16;
typedef _Float16 f16x4 __attribute__((ext_vector_type(4)));
typedef _Float16 f16x8 __attribute__((ext_vector_type(8)));
typedef float    f32x4 __attribute__((ext_vector_type(4)));
typedef unsigned int u32;

#define MFMA_F16(a,b,c) __builtin_amdgcn_mfma_f32_16x16x32_f16((a),(b),(c),0,0,0)

__device__ __forceinline__ u32 pkf16(float a, float b) {
  return __builtin_bit_cast(u32, __builtin_amdgcn_cvt_pkrtz(a, b));
}
union F8U4 { u32 d[4]; f16x8 v; };

__device__ __forceinline__ f16x8 comb(f16x4 a, f16x4 b) {
  f16x8 r;
  #pragma unroll
  for (int i = 0; i < 4; ++i) { r[i] = a[i]; r[4 + i] = b[i]; }
  return r;
}

// ---------------- FFT-layout matrices (exact 0/+-1 entries) ----------------
__device__ __forceinline__ float T_val(int rr, int cc) {
  int p = rr >> 2, f = rr & 3;
  int c = cc >> 2, d = (cc >> 1) & 1, e = cc & 1;
  int q = f & 1;
  int m = (p * c + 2 * q * d) & 3;
  float cs = (m == 0) ? 1.f : (m == 2) ? -1.f : 0.f;
  float sn = (m == 1) ? 1.f : (m == 3) ? -1.f : 0.f;
  if (f < 2) return (e == 0) ? cs : sn;
  return (e == 0) ? -sn : cs;
}
__device__ __forceinline__ float U_val(int rr, int cc) {
  int p = rr >> 2, f = rr & 3;
  int c = cc >> 2, d = (cc >> 1) & 1, e = cc & 1;
  int q = f & 1;
  int m = (p * c + 2 * q * d) & 3;
  float cs = (m == 0) ? 1.f : (m == 2) ? -1.f : 0.f;
  float sn = (m == 1) ? 1.f : (m == 3) ? -1.f : 0.f;
  float v;
  if (f < 2) v = (e == 0) ? cs : -sn;
  else       v = (e == 0) ? sn : cs;
  return v * 0.125f;
}

// ---------------- P1: Wq_eff / Wk_eff (fp32) ----------------
__global__ void prep_qk(const float* __restrict__ Wq, const float* __restrict__ Wk,
                        float* __restrict__ WqE, float* __restrict__ WkE) {
  int b = blockIdx.x;
  int isK = b >> 11;
  int h = (b >> 8) & 7;
  int dd = b & 255;
  const float* W = isK ? Wk : Wq;
  float* E = isK ? WkE : WqE;
  int k = threadIdx.x;
  size_t base = (size_t)h * 65536;
  float v;
  if (h < 3) {
    v = W[base + (size_t)dd * 256 + k];
  } else {
    int g = dd >> 4, i = dd & 15;
    float s = 0.f;
    for (int ip = 0; ip < 16; ++ip) {
      float t = T_val(ip, i);
      if (t != 0.f) s += t * W[base + (size_t)(g * 16 + ip) * 256 + k];
    }
    v = s;
  }
  E[base + (size_t)dd * 256 + k] = v;
}

// ---------------- P2: Mt[h][d'][d] = (Wq_eff . Wk_eff^T)[d][d'] / 16 (fp16)
__global__ void prep_m(const float* __restrict__ WqE, const float* __restrict__ WkE,
                       f16* __restrict__ Mt) {
  __shared__ float Aq[32][33];
  __shared__ float Bk[32][33];
  int h = blockIdx.x >> 6;
  int dpt = (blockIdx.x >> 3) & 7;
  int dt = blockIdx.x & 7;
  int tid = threadIdx.x;
  int drow = tid & 31;
  int dprow4 = (tid >> 5) * 4;
  float acc0 = 0.f, acc1 = 0.f, acc2 = 0.f, acc3 = 0.f;
  int r = tid >> 3;
  int c0 = (tid & 7) * 4;
  for (int kt = 0; kt < 8; ++kt) {
    for (int jj = 0; jj < 4; ++jj) {
      Aq[r][c0 + jj] = WqE[(size_t)h * 65536 + (size_t)(dt * 32 + r) * 256 + kt * 32 + c0 + jj];
      Bk[r][c0 + jj] = WkE[(size_t)h * 65536 + (size_t)(dpt * 32 + r) * 256 + kt * 32 + c0 + jj];
    }
    __syncthreads();
    #pragma unroll
    for (int k = 0; k < 32; ++k) {
      float a = Aq[drow][k];
      acc0 += a * Bk[dprow4 + 0][k];
      acc1 += a * Bk[dprow4 + 1][k];
      acc2 += a * Bk[dprow4 + 2][k];
      acc3 += a * Bk[dprow4 + 3][k];
    }
    __syncthreads();
  }
  int d_ = dt * 32 + drow;
  size_t ob = (size_t)h * 65536 + (size_t)(dpt * 32 + dprow4) * 256 + d_;
  Mt[ob + 0 * 256] = (f16)(acc0 * 0.0625f);
  Mt[ob + 1 * 256] = (f16)(acc1 * 0.0625f);
  Mt[ob + 2 * 256] = (f16)(acc2 * 0.0625f);
  Mt[ob + 3 * 256] = (f16)(acc3 * 0.0625f);
}

// ---------------- P3: Wvt[h][k'][d] = Wv_eff[d][k'] / NUM_HEADS (fp16)
__global__ void prep_v(const float* __restrict__ Wv, f16* __restrict__ Wvt) {
  __shared__ float Ts[16][16];
  __shared__ float Us[16][16];
  int h = blockIdx.x >> 8;
  int kp = blockIdx.x & 255;
  int tid = threadIdx.x;
  Ts[tid >> 4][tid & 15] = T_val(tid >> 4, tid & 15);
  Us[tid >> 4][tid & 15] = U_val(tid >> 4, tid & 15);
  __syncthreads();
  int d = tid;
  int g = d >> 4, i = d & 15;
  int gp = kp >> 4, fp = kp & 15;
  float s = 0.f;
  if (h < 3) {
    s = Wv[(size_t)h * 65536 + (size_t)d * 256 + kp];
  } else {
    for (int ip = 0; ip < 16; ++ip) {
      float tv = Ts[ip][i];
      if (tv != 0.f) {
        float inner = 0.f;
        for (int jj = 0; jj < 16; ++jj) {
          float uv = Us[fp][jj];
          if (uv != 0.f)
            inner += uv * Wv[(size_t)h * 65536 + (size_t)(g * 16 + ip) * 256 + gp * 16 + jj];
        }
        s += tv * inner;
      }
    }
  }
  Wvt[(size_t)h * 65536 + (size_t)kp * 256 + d] = (f16)(s * 0.125f);
}

// ---------------- P4: repack to 16x16x32 fragment-major (coalesced 1KB loads)
// F[h][t16][kt][lane][8] = src[h][t16*16 + (l&15)][kt*32 + (l>>4)*8 + j]
__global__ void repack16(const f16* __restrict__ Mt, const f16* __restrict__ Wvt,
                         f16* __restrict__ MtF, f16* __restrict__ WvF) {
  int bid = blockIdx.x;              // 2048 = 2 * 8h * 16t * 8kt
  int which = bid >> 10;
  int h = (bid >> 7) & 7;
  int t16 = (bid >> 3) & 15;
  int kt = bid & 7;
  int l = threadIdx.x;               // 64
  const f16* src = which ? Wvt : Mt;
  f16* dst = which ? WvF : MtF;
  size_t sb = (size_t)h * 65536 + (size_t)(t16 * 16 + (l & 15)) * 256 + kt * 32 + (l >> 4) * 8;
  size_t db = ((size_t)((h * 16 + t16) * 8 + kt) * 64 + l) * 8;
  *(f16x8*)(dst + db) = *(const f16x8*)(src + sb);
}

// ---------------- Main fused kernel ----------------
// 512 thr (8 waves), 4 batches/block, grid 1024. LDS 141312 B:
//   Xs [128 rows][256] f16, swz granule 8f16: col ^ ((row&7)<<3)   65536 B
//   Y  [128 s][256 d'] f16, same swz                               65536 B
//   Aat [4b][32 s][40] f16 (attention matrix, rows=s, cols=t)      10240 B
// Per head, 2 barriers:
//   P1: wave (dq=w>>1, sh=w&1): Y-slice (4 arow x 4 nt, frag reuse 4x) -> LDS
//       then wave (bp=w>>2, kq=w&3): V[2b][2 t-tiles][4 k'-tiles] -> REGS (fp16)
//   P2: wave (bq=w>>1, mt=w&1): scores (R1-verbatim) + parity softmax -> Aat
//   P3: PV fully in registers (pi-permutation cancels), O persistent in VGPRs
__global__ __launch_bounds__(512, 2) void mha_main(
    const float* __restrict__ xg_all,
    const f16* __restrict__ MtF,
    const f16* __restrict__ WvF,
    float* __restrict__ outG)
{
  extern __shared__ char smem[];
  f16* Xs  = (f16*)smem;
  f16* Y   = (f16*)(smem + 65536);
  f16* Aat = (f16*)(smem + 131072);

  const int tid = threadIdx.x;
  const int w   = tid >> 6;
  const int l   = tid & 63;
  const int l15 = l & 15;
  const int l4  = l >> 4;

  // ---- stage x (4 batches, fp32 -> fp16, swizzled) : R1-verbatim ----
  const float* xg = xg_all + (size_t)blockIdx.x * 32768;
  #pragma unroll 4
  for (int i = 0; i < 16; ++i) {
    int f4 = i * 512 + tid;
    int row = f4 >> 6;
    int col = (f4 & 63) << 2;
    f32x4 v = *(const f32x4*)(xg + (size_t)f4 * 4);
    f16x4 hv;
    hv[0] = (f16)v[0]; hv[1] = (f16)v[1]; hv[2] = (f16)v[2]; hv[3] = (f16)v[3];
    *(f16x4*)(Xs + row * 256 + (col ^ ((row & 7) << 3))) = hv;
  }
  __syncthreads();

  const int dq = w >> 1, sh = w & 1;     // P1-Y split
  const int bp = w >> 2, kq = w & 3;     // P1-V / P3 / store split
  const int bq = w >> 1, mt = w & 1;     // P2 split

  // persistent O accumulators: [b in pair][s-tile][k'-tile]
  f32x4 O[2][2][4];
  #pragma unroll
  for (int b = 0; b < 2; ++b)
    #pragma unroll
    for (int sm = 0; sm < 2; ++sm)
      #pragma unroll
      for (int n = 0; n < 4; ++n)
        O[b][sm][n] = (f32x4){0.f, 0.f, 0.f, 0.f};

  for (int h = 0; h < 8; ++h) {
    // ================= P1a: Y = Mt . x^T (slice) =================
    {
      f32x4 C[4][4];
      #pragma unroll
      for (int a = 0; a < 4; ++a)
        #pragma unroll
        for (int n = 0; n < 4; ++n) C[a][n] = (f32x4){0.f, 0.f, 0.f, 0.f};
      #pragma unroll 2
      for (int kt = 0; kt < 8; ++kt) {
        f16x8 A[4], B[4];
        #pragma unroll
        for (int a = 0; a < 4; ++a)
          A[a] = *(const f16x8*)(MtF + ((size_t)((h * 16 + dq * 4 + a) * 8 + kt) * 64 + l) * 8);
        #pragma unroll
        for (int n = 0; n < 4; ++n) {
          int srow = sh * 64 + n * 16 + l15;
          B[n] = *(const f16x8*)(Xs + srow * 256 + ((kt * 32 + l4 * 8) ^ ((srow & 7) << 3)));
        }
        #pragma unroll
        for (int a = 0; a < 4; ++a)
          #pragma unroll
          for (int n = 0; n < 4; ++n)
            C[a][n] = MFMA_F16(A[a], B[n], C[a][n]);
      }
      #pragma unroll
      for (int a = 0; a < 4; ++a)
        #pragma unroll
        for (int n = 0; n < 4; ++n) {
          int srow = sh * 64 + n * 16 + l15;
          int dcol = dq * 64 + a * 16 + l4 * 4;
          f16x4 hv;
          hv[0] = (f16)C[a][n][0]; hv[1] = (f16)C[a][n][1];
          hv[2] = (f16)C[a][n][2]; hv[3] = (f16)C[a][n][3];
          *(f16x4*)(Y + srow * 256 + (dcol ^ ((srow & 7) << 3))) = hv;
        }
    }
    // ================= P1b: V = x . Wv (slice) -> registers =================
    u32 Vh[2][2][4][2];
    {
      f32x4 VC[2][2][4];
      #pragma unroll
      for (int b = 0; b < 2; ++b)
        #pragma unroll
        for (int tau = 0; tau < 2; ++tau)
          #pragma unroll
          for (int n = 0; n < 4; ++n) VC[b][tau][n] = (f32x4){0.f, 0.f, 0.f, 0.f};
      #pragma unroll 2
      for (int kt = 0; kt < 8; ++kt) {
        f16x8 Bw[4], Ax[2][2];
        #pragma unroll
        for (int n = 0; n < 4; ++n)
          Bw[n] = *(const f16x8*)(WvF + ((size_t)((h * 16 + kq * 4 + n) * 8 + kt) * 64 + l) * 8);
        #pragma unroll
        for (int b = 0; b < 2; ++b)
          #pragma unroll
          for (int tau = 0; tau < 2; ++tau) {
            int xrow = (bp * 2 + b) * 32 + tau * 16 + l15;
            Ax[b][tau] = *(const f16x8*)(Xs + xrow * 256 + ((kt * 32 + l4 * 8) ^ ((xrow & 7) << 3)));
          }
        #pragma unroll
        for (int b = 0; b < 2; ++b)
          #pragma unroll
          for (int tau = 0; tau < 2; ++tau)
            #pragma unroll
            for (int n = 0; n < 4; ++n)
              VC[b][tau][n] = MFMA_F16(Ax[b][tau], Bw[n], VC[b][tau][n]);
      }
      #pragma unroll
      for (int b = 0; b < 2; ++b)
        #pragma unroll
        for (int tau = 0; tau < 2; ++tau)
          #pragma unroll
          for (int n = 0; n < 4; ++n) {
            Vh[b][tau][n][0] = pkf16(VC[b][tau][n][0], VC[b][tau][n][1]);
            Vh[b][tau][n][1] = pkf16(VC[b][tau][n][2], VC[b][tau][n][3]);
          }
    }
    __syncthreads();   // BAR1: Y visible

    // ================= P2: scores + parity softmax (R1-verbatim) =================
    {
      f32x4 S0 = (f32x4){0.f, 0.f, 0.f, 0.f};
      f32x4 S1 = (f32x4){0.f, 0.f, 0.f, 0.f};
      int yrow = bq * 32 + mt * 16 + l15;
      int x0 = bq * 32 + l15;
      int x1 = bq * 32 + 16 + l15;
      #pragma unroll
      for (int kt = 0; kt < 8; ++kt) {
        int ks = kt * 32 + l4 * 8;
        f16x8 ay = *(const f16x8*)(Y + yrow * 256 + (ks ^ ((yrow & 7) << 3)));
        f16x8 b0 = *(const f16x8*)(Xs + x0 * 256 + (ks ^ ((x0 & 7) << 3)));
        f16x8 b1 = *(const f16x8*)(Xs + x1 * 256 + (ks ^ ((x1 & 7) << 3)));
        S0 = MFMA_F16(ay, b0, S0);
        S1 = MFMA_F16(ay, b1, S1);
      }
      #pragma unroll
      for (int r = 0; r < 4; ++r) {
        bool valid = ((l & 1) == (r & 1));      // t parity == s parity
        float v0 = valid ? S0[r] : -1e30f;
        float v1 = valid ? S1[r] : -1e30f;
        float mx = fmaxf(v0, v1);
        mx = fmaxf(mx, __shfl_xor(mx, 1));
        mx = fmaxf(mx, __shfl_xor(mx, 2));
        mx = fmaxf(mx, __shfl_xor(mx, 4));
        mx = fmaxf(mx, __shfl_xor(mx, 8));
        float e0 = valid ? __expf(v0 - mx) : 0.f;
        float e1 = valid ? __expf(v1 - mx) : 0.f;
        float sm = e0 + e1;
        sm += __shfl_xor(sm, 1);
        sm += __shfl_xor(sm, 2);
        sm += __shfl_xor(sm, 4);
        sm += __shfl_xor(sm, 8);
        float inv = 1.f / sm;
        int s = mt * 16 + l4 * 4 + r;
        Aat[(bq * 32 + s) * 40 + l15] = (f16)(e0 * inv);
        Aat[(bq * 32 + s) * 40 + 16 + l15] = (f16)(e1 * inv);
      }
    }
    __syncthreads();   // BAR2: Aat visible, all Y reads done

    // ================= P3: O += A . V  (all in registers) =================
    #pragma unroll
    for (int b = 0; b < 2; ++b) {
      #pragma unroll
      for (int sm = 0; sm < 2; ++sm) {
        int arow = ((bp * 2 + b) * 32 + sm * 16 + l15) * 40 + l4 * 4;
        f16x8 bf = comb(*(const f16x4*)(Aat + arow),
                        *(const f16x4*)(Aat + arow + 16));
        #pragma unroll
        for (int n = 0; n < 4; ++n) {
          F8U4 av;
          av.d[0] = Vh[b][0][n][0];
          av.d[1] = Vh[b][0][n][1];
          av.d[2] = Vh[b][1][n][0];
          av.d[3] = Vh[b][1][n][1];
          O[b][sm][n] = MFMA_F16(av.v, bf, O[b][sm][n]);
        }
      }
    }
    // no barrier needed: next P1 writes Y (reads done at BAR2), Aat rewritten only after next BAR1
  }

  // ---- store O: out[b][s][k'], lane=s from bf-side, regs=k' quad ----
  #pragma unroll
  for (int b = 0; b < 2; ++b) {
    float* ob = outG + ((size_t)blockIdx.x * 4 + bp * 2 + b) * 8192;
    #pragma unroll
    for (int sm = 0; sm < 2; ++sm) {
      int s = sm * 16 + l15;
      #pragma unroll
      for (int n = 0; n < 4; ++n) {
        int kp = kq * 64 + n * 16 + l4 * 4;
        *(f32x4*)(ob + s * 256 + kp) = O[b][sm][n];
      }
    }
  }
}

// ---------------- launch ----------------
extern "C" void kernel_launch(void* const* d_in, const int* in_sizes, int n_in,
                              void* d_out, int out_size, void* d_ws, size_t ws_size,
                              hipStream_t stream) {
  const float* x  = (const float*)d_in[0];
  const float* Wq = (const float*)d_in[1];
  const float* Wk = (const float*)d_in[2];
  const float* Wv = (const float*)d_in[3];
  float* out = (float*)d_out;
  char* ws = (char*)d_ws;
  float* WqE = (float*)ws;                       // 2 MB (dead after prep_m)
  float* WkE = (float*)(ws + 2097152);           // 2 MB (dead after prep_m)
  f16*   Mt  = (f16*)(ws + 4194304);             // 1 MB fp16
  f16*   Wvt = (f16*)(ws + 5242880);             // 1 MB fp16
  f16*   MtF = (f16*)ws;                         // 1 MB, overlays WqE
  f16*   WvF = (f16*)(ws + 2097152);             // 1 MB, overlays WkE

  prep_qk<<<4096, 256, 0, stream>>>(Wq, Wk, WqE, WkE);
  prep_m<<<512, 256, 0, stream>>>(WqE, WkE, Mt);
  prep_v<<<2048, 256, 0, stream>>>(Wv, Wvt);
  repack16<<<2048, 64, 0, stream>>>(Mt, Wvt, MtF, WvF);
  mha_main<<<1024, 512, 141312, stream>>>(x, MtF, WvF, out);
}